// Round 2
// baseline (111.172 us; speedup 1.0000x reference)
//
#include <hip/hip_runtime.h>
#include <math.h>

#define C_CLAMP 10000.0f
#define BYP 0.99f

constexpr int NL  = 32;   // leaves
constexpr int NI  = 31;   // internal nodes
constexpr int BLK = 256;

typedef float f4 __attribute__((ext_vector_type(4)));
typedef float f2 __attribute__((ext_vector_type(2)));

// out = exp(log(l) * log(r)) for complex l, r; then nan_to_num + clip to [-C, C]
__device__ __forceinline__ void eml_op(float lre, float lim, float rre, float rim,
                                       float& ore, float& oim) {
    bool fast = (lim == 0.0f) && (rim == 0.0f) && (lre > 0.0f) && (rre > 0.0f);
    if (fast) {
        // purely real positive operands: result real positive
        float t = __logf(lre) * __logf(rre);
        float e = __expf(t);          // may overflow to +inf -> clipped to C
        ore = fminf(e, C_CLAMP);
        oim = 0.0f;
    } else {
        float a = 0.5f * logf(fmaf(lre, lre, lim * lim));
        float b = atan2f(lim, lre);
        float c = 0.5f * logf(fmaf(rre, rre, rim * rim));
        float d = atan2f(rim, rre);
        float t  = a * c - b * d;
        float th = a * d + b * c;
        float e  = expf(t);
        float re_ = e * cosf(th);
        float im_ = e * sinf(th);
        re_ = __builtin_isnan(re_) ? 0.0f : re_;
        im_ = __builtin_isnan(im_) ? 0.0f : im_;
        ore = fminf(fmaxf(re_, -C_CLAMP), C_CLAMP);
        oim = fminf(fmaxf(im_, -C_CLAMP), C_CLAMP);
    }
}

template<int NP>
__device__ __forceinline__ void do_level(const float* g, int node0,
                                         const float* ire, const float* iim,
                                         float* ore, float* oim) {
#pragma unroll
    for (int p = 0; p < NP; ++p) {
        float sl = g[(node0 + p) * 2 + 0];
        float sr = g[(node0 + p) * 2 + 1];
        bool bl = sl > BYP, br = sr > BYP;
        float oml = 1.0f - sl, omr = 1.0f - sr;
        float Lre = ire[2 * p];
        float Rre = ire[2 * p + 1];
        float Lim = iim ? iim[2 * p]     : 0.0f;
        float Rim = iim ? iim[2 * p + 1] : 0.0f;
        float lre = bl ? 1.0f : fmaf(oml, Lre, sl);
        float lim = bl ? 0.0f : oml * Lim;
        float rre = br ? 1.0f : fmaf(omr, Rre, sr);
        float rim = br ? 0.0f : omr * Rim;
        eml_op(lre, lim, rre, rim, ore[p], oim[p]);
    }
}

// PAIRS=true: interleaved (re,im) complex layout. PAIRS=false: real part only.
template<bool PAIRS, int NP>
__device__ __forceinline__ void store_lvl(float* __restrict__ dst, long long sb,
                                          const float* re, const float* im) {
    if constexpr (PAIRS) {
        float* p = dst + sb * (2 * NP);
        if constexpr (NP >= 2) {
#pragma unroll
            for (int q = 0; q < NP; q += 2) {
                f4 v = { re[q], im[q], re[q + 1], im[q + 1] };
                __builtin_nontemporal_store(v, reinterpret_cast<f4*>(p + 2 * q));
            }
        } else {
            f2 v = { re[0], im[0] };
            __builtin_nontemporal_store(v, reinterpret_cast<f2*>(p));
        }
    } else {
        float* p = dst + sb * NP;
        if constexpr (NP >= 4) {
#pragma unroll
            for (int q = 0; q < NP; q += 4) {
                f4 v = { re[q], re[q + 1], re[q + 2], re[q + 3] };
                __builtin_nontemporal_store(v, reinterpret_cast<f4*>(p + q));
            }
        } else if constexpr (NP == 2) {
            f2 v = { re[0], re[1] };
            __builtin_nontemporal_store(v, reinterpret_cast<f2*>(p));
        } else {
            __builtin_nontemporal_store(re[0], p);
        }
    }
}

template<bool PAIRS>
__global__ __launch_bounds__(BLK) void eml_tree_kernel(
    const float* __restrict__ x, const float* __restrict__ y,
    const float* __restrict__ leaf_logits, const float* __restrict__ blend_logits,
    float* __restrict__ o_pred, float* __restrict__ o_leaf, float* __restrict__ o_gate,
    float* __restrict__ o_l1, float* __restrict__ o_l2, float* __restrict__ o_l3,
    float* __restrict__ o_l4, float* __restrict__ o_l5,
    int B, int blocksPerS)
{
    __shared__ float w[NL * 3];   // softmax leaf probs for this s
    __shared__ float g[NI * 2];   // sigmoid gates for this s

    const int bid   = blockIdx.x;
    const int s     = bid / blocksPerS;
    const int chunk = bid - s * blocksPerS;
    const int tid   = threadIdx.x;

    if (tid < NL) {
        const float* p = leaf_logits + (s * NL + tid) * 3;
        float a0 = p[0], a1 = p[1], a2 = p[2];
        float m  = fmaxf(a0, fmaxf(a1, a2));
        float e0 = expf(a0 - m), e1 = expf(a1 - m), e2 = expf(a2 - m);
        float inv = 1.0f / (e0 + e1 + e2);
        w[tid * 3 + 0] = e0 * inv;
        w[tid * 3 + 1] = e1 * inv;
        w[tid * 3 + 2] = e2 * inv;
    } else if (tid >= 64 && tid < 64 + NI * 2) {
        int i = tid - 64;
        float v = blend_logits[s * NI * 2 + i];
        g[i] = 1.0f / (1.0f + expf(-v));
    }
    __syncthreads();

    if (chunk == 0) {
        if (tid < NL * 3) o_leaf[s * NL * 3 + tid] = w[tid];
        if (tid >= 128 && tid < 128 + NI * 2) o_gate[s * NI * 2 + (tid - 128)] = g[tid - 128];
    }

    const int b = chunk * BLK + tid;
    if (b >= B) return;
    const float xv = x[b];
    const float yv = y[b];

    // leaf values: real affine combos (imag = 0)
    float v0[NL];
#pragma unroll
    for (int l = 0; l < NL; ++l)
        v0[l] = fmaf(w[l * 3 + 2], yv, fmaf(w[l * 3 + 1], xv, w[l * 3 + 0]));

    const long long sb = (long long)s * B + b;

    float r1[16], i1[16];
    do_level<16>(g, 0, v0, nullptr, r1, i1);
    store_lvl<PAIRS, 16>(o_l1, sb, r1, i1);

    float r2[8], i2[8];
    do_level<8>(g, 16, r1, i1, r2, i2);
    store_lvl<PAIRS, 8>(o_l2, sb, r2, i2);

    float r3[4], i3[4];
    do_level<4>(g, 24, r2, i2, r3, i3);
    store_lvl<PAIRS, 4>(o_l3, sb, r3, i3);

    float r4[2], i4[2];
    do_level<2>(g, 28, r3, i3, r4, i4);
    store_lvl<PAIRS, 2>(o_l4, sb, r4, i4);

    float r5[1], i5[1];
    do_level<1>(g, 30, r4, i4, r5, i5);
    store_lvl<PAIRS, 1>(o_l5, sb, r5, i5);
    store_lvl<PAIRS, 1>(o_pred, sb, r5, i5);
}

extern "C" void kernel_launch(void* const* d_in, const int* in_sizes, int n_in,
                              void* d_out, int out_size, void* d_ws, size_t ws_size,
                              hipStream_t stream) {
    const float* x     = (const float*)d_in[0];
    const float* y     = (const float*)d_in[1];
    const float* leaf  = (const float*)d_in[2];
    const float* blend = (const float*)d_in[3];

    const int B = in_sizes[0];
    const int S = in_sizes[2] / (NL * 3);

    float* out = (float*)d_out;
    const long long SB = (long long)S * B;
    const long long scalars = (long long)S * (NL * 3 + NI * 2);   // leaf+gate floats

    const long long size_pairs = SB * 64 + scalars;  // complex stored as (re,im) pairs
    // real-only layout is the default (matches harness float32 flatten of complex64)

    const int blocksPerS = (B + BLK - 1) / BLK;
    dim3 grid(S * blocksPerS), block(BLK);

    if ((long long)out_size >= size_pairs) {
        // complex64 stored as interleaved float pairs
        float* o_pred = out;                               // SB*2
        float* o_leaf = o_pred + SB * 2;                   // S*96
        float* o_gate = o_leaf + (long long)S * NL * 3;    // S*62
        float* o_l1   = o_gate + (long long)S * NI * 2;    // SB*32
        float* o_l2   = o_l1 + SB * 32;
        float* o_l3   = o_l2 + SB * 16;
        float* o_l4   = o_l3 + SB * 8;
        float* o_l5   = o_l4 + SB * 4;
        hipLaunchKernelGGL((eml_tree_kernel<true>), grid, block, 0, stream,
                           x, y, leaf, blend,
                           o_pred, o_leaf, o_gate, o_l1, o_l2, o_l3, o_l4, o_l5,
                           B, blocksPerS);
    } else {
        // real parts only
        float* o_pred = out;                               // SB
        float* o_leaf = o_pred + SB;                       // S*96
        float* o_gate = o_leaf + (long long)S * NL * 3;    // S*62
        float* o_l1   = o_gate + (long long)S * NI * 2;    // SB*16
        float* o_l2   = o_l1 + SB * 16;
        float* o_l3   = o_l2 + SB * 8;
        float* o_l4   = o_l3 + SB * 4;
        float* o_l5   = o_l4 + SB * 2;
        hipLaunchKernelGGL((eml_tree_kernel<false>), grid, block, 0, stream,
                           x, y, leaf, blend,
                           o_pred, o_leaf, o_gate, o_l1, o_l2, o_l3, o_l4, o_l5,
                           B, blocksPerS);
    }
}

// Round 3
// 103.027 us; speedup vs baseline: 1.0791x; 1.0791x over previous
//
#include <hip/hip_runtime.h>
#include <math.h>

#define C_CLAMP 10000.0f
#define BYP 0.99f

constexpr int NL  = 32;   // leaves
constexpr int NI  = 31;   // internal nodes
constexpr int BLK = 256;

typedef float f4 __attribute__((ext_vector_type(4)));
typedef float f2 __attribute__((ext_vector_type(2)));

// out = exp(log(l) * log(r)) for complex l, r; then nan_to_num + clip to [-C, C].
// Fast path (operands real-positive) computed unconditionally; the expensive
// full-complex path sits behind a WAVE-UNIFORM branch so the compiler cannot
// if-convert it into every lane's instruction stream.
__device__ __forceinline__ void eml_op(float lre, float lim, float rre, float rim,
                                       float& ore, float& oim) {
    const bool slow = !((lim == 0.0f) & (rim == 0.0f) & (lre > 0.0f) & (rre > 0.0f));

    // fast: purely real positive operands -> result real positive
    float e = __expf(__logf(lre) * __logf(rre));   // +inf -> clipped below
    ore = fminf(e, C_CLAMP);                       // fminf(NaN, C) = C; garbage lanes overwritten below
    oim = 0.0f;

    if (__any(slow)) {                             // wave-uniform: skipped by scalar branch
        float a = 0.5f * logf(fmaf(lre, lre, lim * lim));
        float b = atan2f(lim, lre);
        float c = 0.5f * logf(fmaf(rre, rre, rim * rim));
        float d = atan2f(rim, rre);
        float t  = a * c - b * d;
        float th = a * d + b * c;
        float ex = expf(t);
        float re_ = ex * cosf(th);
        float im_ = ex * sinf(th);
        re_ = __builtin_isnan(re_) ? 0.0f : re_;
        im_ = __builtin_isnan(im_) ? 0.0f : im_;
        re_ = fminf(fmaxf(re_, -C_CLAMP), C_CLAMP);
        im_ = fminf(fmaxf(im_, -C_CLAMP), C_CLAMP);
        if (slow) { ore = re_; oim = im_; }
    }
}

template<int NP>
__device__ __forceinline__ void do_level(const float* g, int node0,
                                         const float* ire, const float* iim,
                                         float* ore, float* oim) {
#pragma unroll
    for (int p = 0; p < NP; ++p) {
        float sl = g[(node0 + p) * 2 + 0];
        float sr = g[(node0 + p) * 2 + 1];
        bool bl = sl > BYP, br = sr > BYP;
        float oml = 1.0f - sl, omr = 1.0f - sr;
        float Lre = ire[2 * p];
        float Rre = ire[2 * p + 1];
        float Lim = iim ? iim[2 * p]     : 0.0f;
        float Rim = iim ? iim[2 * p + 1] : 0.0f;
        float lre = bl ? 1.0f : fmaf(oml, Lre, sl);
        float lim = bl ? 0.0f : oml * Lim;
        float rre = br ? 1.0f : fmaf(omr, Rre, sr);
        float rim = br ? 0.0f : omr * Rim;
        eml_op(lre, lim, rre, rim, ore[p], oim[p]);
    }
}

// PAIRS=true: interleaved (re,im) complex layout. PAIRS=false: real part only.
template<bool PAIRS, int NP>
__device__ __forceinline__ void store_lvl(float* __restrict__ dst, long long sb,
                                          const float* re, const float* im) {
    if constexpr (PAIRS) {
        float* p = dst + sb * (2 * NP);
        if constexpr (NP >= 2) {
#pragma unroll
            for (int q = 0; q < NP; q += 2) {
                f4 v = { re[q], im[q], re[q + 1], im[q + 1] };
                __builtin_nontemporal_store(v, reinterpret_cast<f4*>(p + 2 * q));
            }
        } else {
            f2 v = { re[0], im[0] };
            __builtin_nontemporal_store(v, reinterpret_cast<f2*>(p));
        }
    } else {
        float* p = dst + sb * NP;
        if constexpr (NP >= 4) {
#pragma unroll
            for (int q = 0; q < NP; q += 4) {
                f4 v = { re[q], re[q + 1], re[q + 2], re[q + 3] };
                __builtin_nontemporal_store(v, reinterpret_cast<f4*>(p + q));
            }
        } else if constexpr (NP == 2) {
            f2 v = { re[0], re[1] };
            __builtin_nontemporal_store(v, reinterpret_cast<f2*>(p));
        } else {
            __builtin_nontemporal_store(re[0], p);
        }
    }
}

template<bool PAIRS>
__global__ __launch_bounds__(BLK) void eml_tree_kernel(
    const float* __restrict__ x, const float* __restrict__ y,
    const float* __restrict__ leaf_logits, const float* __restrict__ blend_logits,
    float* __restrict__ o_pred, float* __restrict__ o_leaf, float* __restrict__ o_gate,
    float* __restrict__ o_l1, float* __restrict__ o_l2, float* __restrict__ o_l3,
    float* __restrict__ o_l4, float* __restrict__ o_l5,
    int B, int blocksPerS)
{
    __shared__ float w[NL * 3];   // softmax leaf probs for this s
    __shared__ float g[NI * 2];   // sigmoid gates for this s

    const int bid   = blockIdx.x;
    const int s     = bid / blocksPerS;
    const int chunk = bid - s * blocksPerS;
    const int tid   = threadIdx.x;

    if (tid < NL) {
        const float* p = leaf_logits + (s * NL + tid) * 3;
        float a0 = p[0], a1 = p[1], a2 = p[2];
        float m  = fmaxf(a0, fmaxf(a1, a2));
        float e0 = expf(a0 - m), e1 = expf(a1 - m), e2 = expf(a2 - m);
        float inv = 1.0f / (e0 + e1 + e2);
        w[tid * 3 + 0] = e0 * inv;
        w[tid * 3 + 1] = e1 * inv;
        w[tid * 3 + 2] = e2 * inv;
    } else if (tid >= 64 && tid < 64 + NI * 2) {
        int i = tid - 64;
        float v = blend_logits[s * NI * 2 + i];
        g[i] = 1.0f / (1.0f + expf(-v));
    }
    __syncthreads();

    if (chunk == 0) {
        if (tid < NL * 3) o_leaf[s * NL * 3 + tid] = w[tid];
        if (tid >= 128 && tid < 128 + NI * 2) o_gate[s * NI * 2 + (tid - 128)] = g[tid - 128];
    }

    const int b = chunk * BLK + tid;
    if (b >= B) return;
    const float xv = x[b];
    const float yv = y[b];

    // leaf values: real affine combos (imag = 0)
    float v0[NL];
#pragma unroll
    for (int l = 0; l < NL; ++l)
        v0[l] = fmaf(w[l * 3 + 2], yv, fmaf(w[l * 3 + 1], xv, w[l * 3 + 0]));

    const long long sb = (long long)s * B + b;

    float r1[16], i1[16];
    do_level<16>(g, 0, v0, nullptr, r1, i1);
    store_lvl<PAIRS, 16>(o_l1, sb, r1, i1);

    float r2[8], i2[8];
    do_level<8>(g, 16, r1, i1, r2, i2);
    store_lvl<PAIRS, 8>(o_l2, sb, r2, i2);

    float r3[4], i3[4];
    do_level<4>(g, 24, r2, i2, r3, i3);
    store_lvl<PAIRS, 4>(o_l3, sb, r3, i3);

    float r4[2], i4[2];
    do_level<2>(g, 28, r3, i3, r4, i4);
    store_lvl<PAIRS, 2>(o_l4, sb, r4, i4);

    float r5[1], i5[1];
    do_level<1>(g, 30, r4, i4, r5, i5);
    store_lvl<PAIRS, 1>(o_l5, sb, r5, i5);
    store_lvl<PAIRS, 1>(o_pred, sb, r5, i5);
}

extern "C" void kernel_launch(void* const* d_in, const int* in_sizes, int n_in,
                              void* d_out, int out_size, void* d_ws, size_t ws_size,
                              hipStream_t stream) {
    const float* x     = (const float*)d_in[0];
    const float* y     = (const float*)d_in[1];
    const float* leaf  = (const float*)d_in[2];
    const float* blend = (const float*)d_in[3];

    const int B = in_sizes[0];
    const int S = in_sizes[2] / (NL * 3);

    float* out = (float*)d_out;
    const long long SB = (long long)S * B;
    const long long size_pairs = SB * 64 + (long long)S * (NL * 3 + NI * 2);

    const int blocksPerS = (B + BLK - 1) / BLK;
    dim3 grid(S * blocksPerS), block(BLK);

    if ((long long)out_size >= size_pairs) {
        // complex64 stored as interleaved float pairs
        float* o_pred = out;                               // SB*2
        float* o_leaf = o_pred + SB * 2;                   // S*96
        float* o_gate = o_leaf + (long long)S * NL * 3;    // S*62
        float* o_l1   = o_gate + (long long)S * NI * 2;    // SB*32
        float* o_l2   = o_l1 + SB * 32;
        float* o_l3   = o_l2 + SB * 16;
        float* o_l4   = o_l3 + SB * 8;
        float* o_l5   = o_l4 + SB * 4;
        hipLaunchKernelGGL((eml_tree_kernel<true>), grid, block, 0, stream,
                           x, y, leaf, blend,
                           o_pred, o_leaf, o_gate, o_l1, o_l2, o_l3, o_l4, o_l5,
                           B, blocksPerS);
    } else {
        // real parts only (harness flattens complex64 outputs as float32 real)
        float* o_pred = out;                               // SB
        float* o_leaf = o_pred + SB;                       // S*96
        float* o_gate = o_leaf + (long long)S * NL * 3;    // S*62
        float* o_l1   = o_gate + (long long)S * NI * 2;    // SB*16
        float* o_l2   = o_l1 + SB * 16;
        float* o_l3   = o_l2 + SB * 8;
        float* o_l4   = o_l3 + SB * 4;
        float* o_l5   = o_l4 + SB * 2;
        hipLaunchKernelGGL((eml_tree_kernel<false>), grid, block, 0, stream,
                           x, y, leaf, blend,
                           o_pred, o_leaf, o_gate, o_l1, o_l2, o_l3, o_l4, o_l5,
                           B, blocksPerS);
    }
}